// Round 19
// baseline (19.016 us; speedup 1.0000x reference)
//
#include <hip/hip_runtime.h>
#include <hip/hip_bf16.h>

typedef unsigned short ushort_t;
typedef unsigned int uint_t;
typedef __attribute__((ext_vector_type(8))) short short8;
typedef __attribute__((ext_vector_type(4))) float f32x4;

#define IN_DIM 256
#define OUT_DIM 256
#define BATCH 512
#define NSPL 11
#define KSLOT 12
#define KDIM (IN_DIM * KSLOT)    // 3072
#define BKU 384                  // ushorts per row per chunk (32 inputs x 12)
#define NCHUNK 8

__device__ __forceinline__ uint_t pk2(float lo, float hi) {
  __hip_bfloat162 h = __float22bfloat162_rn(make_float2(lo, hi));  // v_cvt_pk_bf16_f32, RNE
  union { __hip_bfloat162 h2; uint_t u; } c; c.h2 = h;
  return c.u;
}

__device__ __forceinline__ void gload16(const void* g, void* l) {
  // async global->LDS DMA, 16B per lane; LDS dest = wave-uniform base + lane*16
  __builtin_amdgcn_global_load_lds(
      (const __attribute__((address_space(1))) unsigned int*)g,
      (__attribute__((address_space(3))) unsigned int*)l, 16, 0, 0);
}

// ---- Kernel 1: build A[512][3072], W[256][3072] (bf16, KSLOT-interleaved) ONCE,
// stored PRE-SWIZZLED: dword at ushort-col c lands at col c^((row&7)<<3).
// Granule(16B)-XOR with row-uniform swz -> coalescing unchanged; k2 DMAs linearly
// and reads LDS with the matching XOR. ----
__global__ __launch_bounds__(256) void build_aw(const float* __restrict__ x,
                                                const float* __restrict__ coef,
                                                const float* __restrict__ rw,
                                                const float* __restrict__ uw,
                                                ushort_t* __restrict__ A,
                                                ushort_t* __restrict__ W) {
  __shared__ float rowc[IN_DIM * NSPL];            // 11.3 KB: one o-row of coef
  const int bx = blockIdx.x;
  const int t = threadIdx.x;

  if (bx < BATCH) {
    // A row b=bx, cell i=t: closed-form cubic B-spline + silu slot
    const float xf = x[bx * IN_DIM + t];
    const float tt = (xf + 1.75f) * 4.0f;
    const float fJ = floorf(tt);
    const int J = (int)fJ;
    const float u = tt - fJ;
    const float u2 = u * u, u3 = u2 * u, um = 1.0f - u;
    const float n0 = um * um * um * (1.0f / 6.0f);                        // slot J-3
    const float n1 = 0.5f * u3 - u2 + (4.0f / 6.0f);                      // slot J-2
    const float n2 = -0.5f * u3 + 0.5f * u2 + 0.5f * u + (1.0f / 6.0f);   // slot J-1
    const float n3 = u3 * (1.0f / 6.0f);                                  // slot J
    const float silu = xf / (1.0f + __expf(-xf));

    float v[12];
#pragma unroll
    for (int g = 0; g < NSPL; ++g) {
      float val = 0.0f;
      val = (J == g + 3) ? n0 : val;
      val = (J == g + 2) ? n1 : val;
      val = (J == g + 1) ? n2 : val;
      val = (J == g    ) ? n3 : val;
      v[g] = val;
    }
    v[11] = silu;

    const int swz = (bx & 7) << 3;                  // row-in-tile = bx&15; &7 for swizzle
    uint_t* dstrow = (uint_t*)(A + (size_t)bx * KDIM);
#pragma unroll
    for (int j = 0; j < 6; ++j)
      dstrow[((t * KSLOT + 2 * j) ^ swz) >> 1] = pk2(v[2 * j], v[2 * j + 1]);
  } else {
    // W row o=bx-512: coalesced row-stage through LDS, then per-cell pack
    const int o = bx - BATCH;
    const float* src = coef + (size_t)o * IN_DIM * NSPL;     // 2816 floats
#pragma unroll
    for (int j = 0; j < 11; ++j) rowc[t + j * 256] = src[t + j * 256];
    __syncthreads();

    const float us = uw[o * IN_DIM + t];
    const float r  = rw[o * IN_DIM + t];
    const float* c = &rowc[t * NSPL];               // stride 11: bank-benign
    const int swz = (o & 7) << 3;
    uint_t* dstrow = (uint_t*)(W + (size_t)o * KDIM);
    uint_t pv[6];
    pv[0] = pk2(us * c[0], us * c[1]);
    pv[1] = pk2(us * c[2], us * c[3]);
    pv[2] = pk2(us * c[4], us * c[5]);
    pv[3] = pk2(us * c[6], us * c[7]);
    pv[4] = pk2(us * c[8], us * c[9]);
    pv[5] = pk2(us * c[10], r);
#pragma unroll
    for (int j = 0; j < 6; ++j)
      dstrow[((t * KSLOT + 2 * j) ^ swz) >> 1] = pv[j];
  }
}

// ---- Kernel 2: out = A · Wᵀ. 512 blocks x 4 waves; 16x16 tile; 3-buffer LDS ring
// fed by global_load_lds DMA (no VGPR staging, no commits), counted vmcnt(6)
// (never drained to 0 in the loop), raw s_barrier per phase, split-K. ----
__global__ __launch_bounds__(256, 2) void gemm(const ushort_t* __restrict__ A,
                                               const ushort_t* __restrict__ W,
                                               float* __restrict__ out) {
  __shared__ __attribute__((aligned(16))) ushort_t As[3][16 * BKU];   // 36.9 KB
  __shared__ __attribute__((aligned(16))) ushort_t Ws[3][16 * BKU];   // 36.9 KB
  __shared__ f32x4 red[3][64];

  const int tid = threadIdx.x;
  const int lane = tid & 63;
  const int w = tid >> 6;                          // wave 0..3 = K-slice owner
  const int B = blockIdx.x;
  const int mt = B >> 4;
  const int nt = ((B & 7) << 1) | ((B >> 3) & 1);  // XCD-aware (bijective, 512%8==0)
  const int b0 = mt * 16, o0 = nt * 16;
  const int mn = lane & 15;
  const int klane = (lane >> 4) * 8;

  // Staging geometry (chunk-invariant): wave w covers slabs i=0..2, each 512 ushorts.
  // Global A/W are PRE-SWIZZLED by k1, so the DMA source is linear+coalesced and
  // the LDS image (linear copy) is already the swizzled layout.
  int srcOff[3], ldsBase[3];
#pragma unroll
  for (int i = 0; i < 3; ++i) {
    const int F = ((w * 3 + i) * 64 + lane) * 8;   // per-lane flat ushort index
    const int rowi = F / BKU;                      // 0..15
    const int coli = F % BKU;
    srcOff[i] = rowi * KDIM + coli;                // per-lane global offset (linear)
    ldsBase[i] = (w * 3 + i) * 512;                // wave-uniform LDS slab base
  }
  const ushort_t* Ap = A + (size_t)b0 * KDIM;
  const ushort_t* Wp = W + (size_t)o0 * KDIM;

  // MFMA read offsets (XOR matches k1's pre-swizzle)
  const int mrow = mn * BKU;
  const int msw = (mn & 7) << 3;

  f32x4 acc = {0.f, 0.f, 0.f, 0.f};

#define DMA6(C, BUF) {                                                        \
    const int kb = (C) * BKU;                                                 \
    gload16(Ap + srcOff[0] + kb, &As[BUF][ldsBase[0]]);                       \
    gload16(Ap + srcOff[1] + kb, &As[BUF][ldsBase[1]]);                       \
    gload16(Ap + srcOff[2] + kb, &As[BUF][ldsBase[2]]);                       \
    gload16(Wp + srcOff[0] + kb, &Ws[BUF][ldsBase[0]]);                       \
    gload16(Wp + srcOff[1] + kb, &Ws[BUF][ldsBase[1]]);                       \
    gload16(Wp + srcOff[2] + kb, &Ws[BUF][ldsBase[2]]); }

#define MFMA3(BUF) { _Pragma("unroll")                                        \
    for (int q = 0; q < 3; ++q) {                                             \
      const int kidx = w * 96 + q * 32 + klane;                               \
      const int idx = mrow + (kidx ^ msw);                                    \
      short8 af  = *(const short8*)&As[BUF][idx];                             \
      short8 bfr = *(const short8*)&Ws[BUF][idx];                             \
      acc = __builtin_amdgcn_mfma_f32_16x16x32_bf16(af, bfr, acc, 0, 0, 0); }}

  // phase top: wait own chunk-c DMAs (6 newer stay in flight), converge, then
  // issue chunk c+2 (its buffer's last reader finished before this barrier).
#define PHASE_W6(C, BUF, NBUF, DO_ISSUE) {                                    \
    asm volatile("s_waitcnt vmcnt(6)" ::: "memory");                          \
    __builtin_amdgcn_s_barrier();                                             \
    __builtin_amdgcn_sched_barrier(0);                                        \
    if (DO_ISSUE) DMA6((C) + 2, NBUF)                                         \
    MFMA3(BUF) }

  // prologue: chunks 0,1 in flight (12 DMAs outstanding)
  DMA6(0, 0)
  DMA6(1, 1)

  PHASE_W6(0, 0, 2, 1)       // wait c0, issue c2->buf2, mfma buf0
  PHASE_W6(1, 1, 0, 1)       // wait c1, issue c3->buf0, mfma buf1
  PHASE_W6(2, 2, 1, 1)
  PHASE_W6(3, 0, 2, 1)
  PHASE_W6(4, 1, 0, 1)
  PHASE_W6(5, 2, 1, 1)
  PHASE_W6(6, 0, 0, 0)       // wait c6 (c7's 6 in flight), mfma buf0
  {                          // final phase: drain and finish
    asm volatile("s_waitcnt vmcnt(0)" ::: "memory");
    __builtin_amdgcn_s_barrier();
    __builtin_amdgcn_sched_barrier(0);
    MFMA3(1)
  }

  // cross-wave split-K reduce, then write
  if (w > 0) red[w - 1][lane] = acc;
  __syncthreads();

  if (w == 0) {
    const f32x4 t0 = red[0][lane];
    const f32x4 t1 = red[1][lane];
    const f32x4 t2 = red[2][lane];
#pragma unroll
    for (int q = 0; q < 4; ++q) acc[q] += t0[q] + t1[q] + t2[q];

    // C/D layout (HW-verified): col = lane&15, row = (lane>>4)*4 + reg
    const int col = o0 + mn;
    const int rbase = b0 + (lane >> 4) * 4;
#pragma unroll
    for (int r = 0; r < 4; ++r) {
      out[(size_t)(rbase + r) * OUT_DIM + col] = acc[r];
    }
  }
}

extern "C" void kernel_launch(void* const* d_in, const int* in_sizes, int n_in,
                              void* d_out, int out_size, void* d_ws, size_t ws_size,
                              hipStream_t stream) {
  const float* x    = (const float*)d_in[0];
  const float* coef = (const float*)d_in[1];
  const float* rw   = (const float*)d_in[2];
  const float* uw   = (const float*)d_in[3];
  float* out = (float*)d_out;

  ushort_t* A = (ushort_t*)d_ws;                             // 512*3072*2 = 3.0 MB
  ushort_t* W = A + (size_t)BATCH * KDIM;                    // 256*3072*2 = 1.5 MB

  build_aw<<<BATCH + OUT_DIM, 256, 0, stream>>>(x, coef, rw, uw, A, W);
  gemm<<<512, 256, 0, stream>>>(A, W, out);
}

// Round 20
// 18.024 us; speedup vs baseline: 1.0550x; 1.0550x over previous
//
#include <hip/hip_runtime.h>
#include <hip/hip_bf16.h>

typedef unsigned short ushort_t;
typedef unsigned int uint_t;
typedef __attribute__((ext_vector_type(8))) short short8;
typedef __attribute__((ext_vector_type(4))) float f32x4;

#define IN_DIM 256
#define OUT_DIM 256
#define BATCH 512
#define NSPL 11
#define KSLOT 12
#define KDIM (IN_DIM * KSLOT)    // 3072
#define BKU 384                  // ushorts per row per chunk (32 inputs x 12)
#define NCHUNK 8

__device__ __forceinline__ uint_t pk2(float lo, float hi) {
  __hip_bfloat162 h = __float22bfloat162_rn(make_float2(lo, hi));  // v_cvt_pk_bf16_f32, RNE
  union { __hip_bfloat162 h2; uint_t u; } c; c.h2 = h;
  return c.u;
}

// ---- Kernel 1: build A[512][3072] and W[256][3072] (bf16, KSLOT-interleaved) ONCE ----
__global__ __launch_bounds__(256) void build_aw(const float* __restrict__ x,
                                                const float* __restrict__ coef,
                                                const float* __restrict__ rw,
                                                const float* __restrict__ uw,
                                                ushort_t* __restrict__ A,
                                                ushort_t* __restrict__ W) {
  __shared__ float rowc[IN_DIM * NSPL];            // 11.3 KB: one o-row of coef
  const int bx = blockIdx.x;
  const int t = threadIdx.x;

  if (bx < BATCH) {
    // A row b=bx, cell i=t: closed-form cubic B-spline + silu slot
    const float xf = x[bx * IN_DIM + t];
    const float tt = (xf + 1.75f) * 4.0f;
    const float fJ = floorf(tt);
    const int J = (int)fJ;
    const float u = tt - fJ;
    const float u2 = u * u, u3 = u2 * u, um = 1.0f - u;
    const float n0 = um * um * um * (1.0f / 6.0f);                        // slot J-3
    const float n1 = 0.5f * u3 - u2 + (4.0f / 6.0f);                      // slot J-2
    const float n2 = -0.5f * u3 + 0.5f * u2 + 0.5f * u + (1.0f / 6.0f);   // slot J-1
    const float n3 = u3 * (1.0f / 6.0f);                                  // slot J
    const float silu = xf / (1.0f + __expf(-xf));

    float v[12];
#pragma unroll
    for (int g = 0; g < NSPL; ++g) {
      float val = 0.0f;
      val = (J == g + 3) ? n0 : val;
      val = (J == g + 2) ? n1 : val;
      val = (J == g + 1) ? n2 : val;
      val = (J == g    ) ? n3 : val;
      v[g] = val;
    }
    v[11] = silu;

    uint_t* dst = (uint_t*)(A + (size_t)bx * KDIM + t * KSLOT);
#pragma unroll
    for (int j = 0; j < 6; ++j) dst[j] = pk2(v[2 * j], v[2 * j + 1]);
  } else {
    // W row o=bx-512: coalesced row-stage through LDS, then per-cell pack
    const int o = bx - BATCH;
    const float* src = coef + (size_t)o * IN_DIM * NSPL;     // 2816 floats
#pragma unroll
    for (int j = 0; j < 11; ++j) rowc[t + j * 256] = src[t + j * 256];
    __syncthreads();

    const float us = uw[o * IN_DIM + t];
    const float r  = rw[o * IN_DIM + t];
    const float* c = &rowc[t * NSPL];               // stride 11: bank-benign
    uint_t* dst = (uint_t*)(W + (size_t)o * KDIM + t * KSLOT);
    dst[0] = pk2(us * c[0], us * c[1]);
    dst[1] = pk2(us * c[2], us * c[3]);
    dst[2] = pk2(us * c[4], us * c[5]);
    dst[3] = pk2(us * c[6], us * c[7]);
    dst[4] = pk2(us * c[8], us * c[9]);
    dst[5] = pk2(us * c[10], r);
  }
}

// ---- Kernel 2: out = A · Wᵀ. 512 blocks x 4 waves; 16x16 tile; double-buffered
// LDS (T2 XOR-swizzle) with DEPTH-3 register staging: chunk c issues at phase
// c-3 and commits at phase c-1 -> its loads get TWO full phases to land.
// Split-K across waves, one barrier per phase. ----
__global__ __launch_bounds__(256, 2) void gemm(const ushort_t* __restrict__ A,
                                               const ushort_t* __restrict__ W,
                                               float* __restrict__ out) {
  __shared__ __attribute__((aligned(16))) ushort_t As[2][16 * BKU];   // 24.6 KB
  __shared__ __attribute__((aligned(16))) ushort_t Ws[2][16 * BKU];   // 24.6 KB
  __shared__ f32x4 red[3][64];

  const int tid = threadIdx.x;
  const int lane = tid & 63;
  const int w = tid >> 6;                          // wave 0..3 = K-slice owner
  const int B = blockIdx.x;
  const int mt = B >> 4;
  const int nt = ((B & 7) << 1) | ((B >> 3) & 1);  // XCD-aware (bijective, 512%8==0)
  const int b0 = mt * 16, o0 = nt * 16;
  const int mn = lane & 15;
  const int klane = (lane >> 4) * 8;

  // Staging geometry (chunk-invariant): wave w covers 3 x 512-ushort slabs.
  int srcOff[3], ldsOff[3];
#pragma unroll
  for (int i = 0; i < 3; ++i) {
    const int F = ((w * 3 + i) * 64 + lane) * 8;
    const int rowi = F / BKU;                      // 0..15
    const int coli = F % BKU;
    srcOff[i] = rowi * KDIM + coli;                // global: linear, coalesced
    ldsOff[i] = rowi * BKU + (coli ^ ((rowi & 7) << 3));   // T2 swizzle (ushort units)
  }
  const ushort_t* Ap = A + (size_t)b0 * KDIM;
  const ushort_t* Wp = W + (size_t)o0 * KDIM;

  // MFMA read offsets (swizzled to match)
  const int mrow = mn * BKU;
  const int msw = (mn & 7) << 3;

  f32x4 acc = {0.f, 0.f, 0.f, 0.f};

  // three named register stages (stage = chunk % 3; rule #20: all static)
  short8 s0a0, s0a1, s0a2, s0w0, s0w1, s0w2;
  short8 s1a0, s1a1, s1a2, s1w0, s1w1, s1w2;
  short8 s2a0, s2a1, s2a2, s2w0, s2w1, s2w2;

#define ISSUE(S, C) { const int kb = (C) * BKU;                               \
    S##a0 = *(const short8*)(Ap + srcOff[0] + kb);                            \
    S##a1 = *(const short8*)(Ap + srcOff[1] + kb);                            \
    S##a2 = *(const short8*)(Ap + srcOff[2] + kb);                            \
    S##w0 = *(const short8*)(Wp + srcOff[0] + kb);                            \
    S##w1 = *(const short8*)(Wp + srcOff[1] + kb);                            \
    S##w2 = *(const short8*)(Wp + srcOff[2] + kb); }

#define COMMIT(S, BUF) {                                                      \
    *(short8*)&As[BUF][ldsOff[0]] = S##a0;                                    \
    *(short8*)&As[BUF][ldsOff[1]] = S##a1;                                    \
    *(short8*)&As[BUF][ldsOff[2]] = S##a2;                                    \
    *(short8*)&Ws[BUF][ldsOff[0]] = S##w0;                                    \
    *(short8*)&Ws[BUF][ldsOff[1]] = S##w1;                                    \
    *(short8*)&Ws[BUF][ldsOff[2]] = S##w2; }

#define MFMA3(BUF) { _Pragma("unroll")                                        \
    for (int q = 0; q < 3; ++q) {                                             \
      const int kidx = w * 96 + q * 32 + klane;                               \
      const int idx = mrow + (kidx ^ msw);                                    \
      short8 af  = *(const short8*)&As[BUF][idx];                             \
      short8 bfr = *(const short8*)&Ws[BUF][idx];                             \
      acc = __builtin_amdgcn_mfma_f32_16x16x32_bf16(af, bfr, acc, 0, 0, 0); }}

  // prologue: chunks 0,1,2 in flight; chunk 0 committed (one unavoidable stall)
  ISSUE(s0, 0)
  ISSUE(s1, 1)
  ISSUE(s2, 2)
  COMMIT(s0, 0)
  __syncthreads();

  // phase p: consume chunk p from buf p&1; issue chunk p+3; commit chunk p+1
  // (issued 2 phases ago) into buf (p+1)&1 — disjoint from the buf being read.
  ISSUE(s0, 3)  MFMA3(0)  COMMIT(s1, 1)  __syncthreads();   // phase 0
  ISSUE(s1, 4)  MFMA3(1)  COMMIT(s2, 0)  __syncthreads();   // phase 1
  ISSUE(s2, 5)  MFMA3(0)  COMMIT(s0, 1)  __syncthreads();   // phase 2
  ISSUE(s0, 6)  MFMA3(1)  COMMIT(s1, 0)  __syncthreads();   // phase 3
  ISSUE(s1, 7)  MFMA3(0)  COMMIT(s2, 1)  __syncthreads();   // phase 4
                MFMA3(1)  COMMIT(s0, 0)  __syncthreads();   // phase 5
                MFMA3(0)  COMMIT(s1, 1)  __syncthreads();   // phase 6
                MFMA3(1)                                    // phase 7 (barrier folds into reduce)

  // cross-wave split-K reduce, then write
  if (w > 0) red[w - 1][lane] = acc;
  __syncthreads();

  if (w == 0) {
    const f32x4 t0 = red[0][lane];
    const f32x4 t1 = red[1][lane];
    const f32x4 t2 = red[2][lane];
#pragma unroll
    for (int q = 0; q < 4; ++q) acc[q] += t0[q] + t1[q] + t2[q];

    // C/D layout (HW-verified): col = lane&15, row = (lane>>4)*4 + reg
    const int col = o0 + mn;
    const int rbase = b0 + (lane >> 4) * 4;
#pragma unroll
    for (int r = 0; r < 4; ++r) {
      out[(size_t)(rbase + r) * OUT_DIM + col] = acc[r];
    }
  }
}

extern "C" void kernel_launch(void* const* d_in, const int* in_sizes, int n_in,
                              void* d_out, int out_size, void* d_ws, size_t ws_size,
                              hipStream_t stream) {
  const float* x    = (const float*)d_in[0];
  const float* coef = (const float*)d_in[1];
  const float* rw   = (const float*)d_in[2];
  const float* uw   = (const float*)d_in[3];
  float* out = (float*)d_out;

  ushort_t* A = (ushort_t*)d_ws;                             // 512*3072*2 = 3.0 MB
  ushort_t* W = A + (size_t)BATCH * KDIM;                    // 256*3072*2 = 1.5 MB

  build_aw<<<BATCH + OUT_DIM, 256, 0, stream>>>(x, coef, rw, uw, A, W);
  gemm<<<512, 256, 0, stream>>>(A, W, out);
}

// Round 21
// 17.432 us; speedup vs baseline: 1.0908x; 1.0339x over previous
//
#include <hip/hip_runtime.h>
#include <hip/hip_bf16.h>

typedef unsigned short ushort_t;
typedef unsigned int uint_t;
typedef __attribute__((ext_vector_type(8))) short short8;
typedef __attribute__((ext_vector_type(4))) float f32x4;

#define IN_DIM 256
#define OUT_DIM 256
#define BATCH 512
#define NSPL 11
#define KSLOT 12
#define KDIM (IN_DIM * KSLOT)    // 3072
#define BKU 384                  // ushorts per row per chunk (32 inputs x 12)
#define NCHUNK 8

__device__ __forceinline__ uint_t pk2(float lo, float hi) {
  __hip_bfloat162 h = __float22bfloat162_rn(make_float2(lo, hi));  // v_cvt_pk_bf16_f32, RNE
  union { __hip_bfloat162 h2; uint_t u; } c; c.h2 = h;
  return c.u;
}

// ---- Kernel 1: build A[512][3072] and W[256][3072] (bf16, KSLOT-interleaved) ONCE.
// Cells are assembled in LDS (A: scatter-pack, W: direct cell write), then the
// row image is written out LINEARLY (6 passes x 1KiB/wave, fully coalesced) —
// replaces the old 24B-stride per-cell global stores. ----
__global__ __launch_bounds__(256) void build_aw(const float* __restrict__ x,
                                                const float* __restrict__ coef,
                                                const float* __restrict__ rw,
                                                const float* __restrict__ uw,
                                                ushort_t* __restrict__ A,
                                                ushort_t* __restrict__ W) {
  __shared__ float rowc[IN_DIM * NSPL];                    // 11.3 KB (W path)
  __shared__ __attribute__((aligned(8))) ushort_t stage[IN_DIM * KSLOT + 8]; // 6.2 KB + dump
  const int bx = blockIdx.x;
  const int t = threadIdx.x;

  if (bx < BATCH) {
    // A row b=bx, cell i=t: closed-form cubic B-spline + silu, scatter-packed in LDS
    const float xf = x[bx * IN_DIM + t];
    const float tt = (xf + 1.75f) * 4.0f;
    const float fJ = floorf(tt);
    const int J = (int)fJ;
    const float u = tt - fJ;
    const float u2 = u * u, u3 = u2 * u, um = 1.0f - u;
    const float n0 = um * um * um * (1.0f / 6.0f);                        // slot J-3
    const float n1 = 0.5f * u3 - u2 + (4.0f / 6.0f);                      // slot J-2
    const float n2 = -0.5f * u3 + 0.5f * u2 + 0.5f * u + (1.0f / 6.0f);   // slot J-1
    const float n3 = u3 * (1.0f / 6.0f);                                  // slot J
    const float silu = xf / (1.0f + __expf(-xf));

    ushort_t* cb = &stage[t * KSLOT];
    ushort_t* dump = &stage[IN_DIM * KSLOT];
    // zero the 12-slot cell: 3 x 8B (24t byte base -> 8B aligned)
    *(unsigned long long*)&cb[0] = 0ull;
    *(unsigned long long*)&cb[4] = 0ull;
    *(unsigned long long*)&cb[8] = 0ull;

    const uint_t p01 = pk2(n0, n1);
    const uint_t p23 = pk2(n2, n3);
    const uint_t psl = pk2(silu, silu);
    const int base = J - 3;
    ushort_t* w0 = ((unsigned)(base + 0) <= 10u) ? (cb + base + 0) : (dump + 0);
    ushort_t* w1 = ((unsigned)(base + 1) <= 10u) ? (cb + base + 1) : (dump + 1);
    ushort_t* w2 = ((unsigned)(base + 2) <= 10u) ? (cb + base + 2) : (dump + 2);
    ushort_t* w3 = ((unsigned)(base + 3) <= 10u) ? (cb + base + 3) : (dump + 3);
    *w0 = (ushort_t)p01;
    *w1 = (ushort_t)(p01 >> 16);
    *w2 = (ushort_t)p23;
    *w3 = (ushort_t)(p23 >> 16);
    cb[11] = (ushort_t)psl;
    __syncthreads();

    // coalesced writeout: 6 passes of 256 consecutive dwords
    uint_t* dst = (uint_t*)(A + (size_t)bx * KDIM);
    const uint_t* src = (const uint_t*)stage;
#pragma unroll
    for (int p = 0; p < 6; ++p) dst[t + p * 256] = src[t + p * 256];
  } else {
    // W row o=bx-512: coalesced coef row-stage -> per-cell pack into LDS -> linear writeout
    const int o = bx - BATCH;
    const float* src = coef + (size_t)o * IN_DIM * NSPL;     // 2816 floats, coalesced
#pragma unroll
    for (int j = 0; j < 11; ++j) rowc[t + j * 256] = src[t + j * 256];
    __syncthreads();

    const float us = uw[o * IN_DIM + t];
    const float r  = rw[o * IN_DIM + t];
    const float* c = &rowc[t * NSPL];                 // stride 11: bank-benign
    uint_t* cell = (uint_t*)&stage[t * KSLOT];        // 6 dwords per cell
    cell[0] = pk2(us * c[0], us * c[1]);
    cell[1] = pk2(us * c[2], us * c[3]);
    cell[2] = pk2(us * c[4], us * c[5]);
    cell[3] = pk2(us * c[6], us * c[7]);
    cell[4] = pk2(us * c[8], us * c[9]);
    cell[5] = pk2(us * c[10], r);
    __syncthreads();

    uint_t* dst = (uint_t*)(W + (size_t)o * KDIM);
    const uint_t* s2 = (const uint_t*)stage;
#pragma unroll
    for (int p = 0; p < 6; ++p) dst[t + p * 256] = s2[t + p * 256];
  }
}

// ---- Kernel 2: out = A · Wᵀ. (R18's best, unchanged.) 512 blocks x 4 waves;
// 16x16 tile; double-buffered LDS (T2 XOR-swizzle) with depth-2 register
// staging: loads for chunk c+2 issue at phase c, commit at phase c+1.
// Split-K across waves, one barrier per phase (last trimmed). ----
__global__ __launch_bounds__(256, 3) void gemm(const ushort_t* __restrict__ A,
                                               const ushort_t* __restrict__ W,
                                               float* __restrict__ out) {
  __shared__ __attribute__((aligned(16))) ushort_t As[2][16 * BKU];   // 24.6 KB
  __shared__ __attribute__((aligned(16))) ushort_t Ws[2][16 * BKU];   // 24.6 KB
  __shared__ f32x4 red[3][64];

  const int tid = threadIdx.x;
  const int lane = tid & 63;
  const int w = tid >> 6;                          // wave 0..3 = K-slice owner
  const int B = blockIdx.x;
  const int mt = B >> 4;
  const int nt = ((B & 7) << 1) | ((B >> 3) & 1);  // XCD-aware (bijective, 512%8==0)
  const int b0 = mt * 16, o0 = nt * 16;
  const int mn = lane & 15;
  const int klane = (lane >> 4) * 8;

  int srcOff[3], ldsOff[3];
#pragma unroll
  for (int i = 0; i < 3; ++i) {
    const int F = ((w * 3 + i) * 64 + lane) * 8;
    const int rowi = F / BKU;                      // 0..15
    const int coli = F % BKU;
    srcOff[i] = rowi * KDIM + coli;                // global: linear, coalesced
    ldsOff[i] = rowi * BKU + (coli ^ ((rowi & 7) << 3));   // T2 swizzle (ushort units)
  }
  const ushort_t* Ap = A + (size_t)b0 * KDIM;
  const ushort_t* Wp = W + (size_t)o0 * KDIM;

  const int mrow = mn * BKU;
  const int msw = (mn & 7) << 3;

  f32x4 acc = {0.f, 0.f, 0.f, 0.f};

  short8 s0a0, s0a1, s0a2, s0w0, s0w1, s0w2;
  short8 s1a0, s1a1, s1a2, s1w0, s1w1, s1w2;

#define ISSUE_S0(C) { const int kb = (C) * BKU;                               \
    s0a0 = *(const short8*)(Ap + srcOff[0] + kb);                             \
    s0a1 = *(const short8*)(Ap + srcOff[1] + kb);                             \
    s0a2 = *(const short8*)(Ap + srcOff[2] + kb);                             \
    s0w0 = *(const short8*)(Wp + srcOff[0] + kb);                             \
    s0w1 = *(const short8*)(Wp + srcOff[1] + kb);                             \
    s0w2 = *(const short8*)(Wp + srcOff[2] + kb); }
#define ISSUE_S1(C) { const int kb = (C) * BKU;                               \
    s1a0 = *(const short8*)(Ap + srcOff[0] + kb);                             \
    s1a1 = *(const short8*)(Ap + srcOff[1] + kb);                             \
    s1a2 = *(const short8*)(Ap + srcOff[2] + kb);                             \
    s1w0 = *(const short8*)(Wp + srcOff[0] + kb);                             \
    s1w1 = *(const short8*)(Wp + srcOff[1] + kb);                             \
    s1w2 = *(const short8*)(Wp + srcOff[2] + kb); }
#define COMMIT_S0(BUF) {                                                      \
    *(short8*)&As[BUF][ldsOff[0]] = s0a0;                                     \
    *(short8*)&As[BUF][ldsOff[1]] = s0a1;                                     \
    *(short8*)&As[BUF][ldsOff[2]] = s0a2;                                     \
    *(short8*)&Ws[BUF][ldsOff[0]] = s0w0;                                     \
    *(short8*)&Ws[BUF][ldsOff[1]] = s0w1;                                     \
    *(short8*)&Ws[BUF][ldsOff[2]] = s0w2; }
#define COMMIT_S1(BUF) {                                                      \
    *(short8*)&As[BUF][ldsOff[0]] = s1a0;                                     \
    *(short8*)&As[BUF][ldsOff[1]] = s1a1;                                     \
    *(short8*)&As[BUF][ldsOff[2]] = s1a2;                                     \
    *(short8*)&Ws[BUF][ldsOff[0]] = s1w0;                                     \
    *(short8*)&Ws[BUF][ldsOff[1]] = s1w1;                                     \
    *(short8*)&Ws[BUF][ldsOff[2]] = s1w2; }

#define MFMA3(BUF) { _Pragma("unroll")                                        \
    for (int q = 0; q < 3; ++q) {                                             \
      const int kidx = w * 96 + q * 32 + klane;                               \
      const int idx = mrow + (kidx ^ msw);                                    \
      short8 af  = *(const short8*)&As[BUF][idx];                             \
      short8 bfr = *(const short8*)&Ws[BUF][idx];                             \
      acc = __builtin_amdgcn_mfma_f32_16x16x32_bf16(af, bfr, acc, 0, 0, 0); }}

  // prologue: chunk 0 staged+committed (one unavoidable stall); chunk 1 in flight
  ISSUE_S0(0)
  COMMIT_S0(0)
  ISSUE_S1(1)
  __syncthreads();

#pragma unroll
  for (int cc = 0; cc < 4; ++cc) {
    if (cc < 3) { ISSUE_S0(2 * cc + 2) }
    MFMA3(0)
    COMMIT_S1(1)
    __syncthreads();

    if (cc < 3) {
      ISSUE_S1(2 * cc + 3)
      MFMA3(1)
      COMMIT_S0(0)
      __syncthreads();
    } else {
      MFMA3(1)
    }
  }

  if (w > 0) red[w - 1][lane] = acc;
  __syncthreads();

  if (w == 0) {
    const f32x4 t0 = red[0][lane];
    const f32x4 t1 = red[1][lane];
    const f32x4 t2 = red[2][lane];
#pragma unroll
    for (int q = 0; q < 4; ++q) acc[q] += t0[q] + t1[q] + t2[q];

    // C/D layout (HW-verified): col = lane&15, row = (lane>>4)*4 + reg
    const int col = o0 + mn;
    const int rbase = b0 + (lane >> 4) * 4;
#pragma unroll
    for (int r = 0; r < 4; ++r) {
      out[(size_t)(rbase + r) * OUT_DIM + col] = acc[r];
    }
  }
}

extern "C" void kernel_launch(void* const* d_in, const int* in_sizes, int n_in,
                              void* d_out, int out_size, void* d_ws, size_t ws_size,
                              hipStream_t stream) {
  const float* x    = (const float*)d_in[0];
  const float* coef = (const float*)d_in[1];
  const float* rw   = (const float*)d_in[2];
  const float* uw   = (const float*)d_in[3];
  float* out = (float*)d_out;

  ushort_t* A = (ushort_t*)d_ws;                             // 512*3072*2 = 3.0 MB
  ushort_t* W = A + (size_t)BATCH * KDIM;                    // 256*3072*2 = 1.5 MB

  build_aw<<<BATCH + OUT_DIM, 256, 0, stream>>>(x, coef, rw, uw, A, W);
  gemm<<<512, 256, 0, stream>>>(A, W, out);
}